// Round 11
// baseline (263.155 us; speedup 1.0000x reference)
//
#include <hip/hip_runtime.h>
#include <cmath>

#define NB 256
#define NS 8192
#define NF 2048
#define NK 20

typedef _Float16 half8 __attribute__((ext_vector_type(8)));
typedef _Float16 half4 __attribute__((ext_vector_type(4)));
typedef float f32x4 __attribute__((ext_vector_type(4)));

__device__ __forceinline__ float waveSum(float v) {
#pragma unroll
  for (int off = 32; off > 0; off >>= 1) v += __shfl_xor(v, off, 64);
  return v;
}
__device__ __forceinline__ float waveMax(float v) {
#pragma unroll
  for (int off = 32; off > 0; off >>= 1) v = fmaxf(v, __shfl_xor(v, off, 64));
  return v;
}

// ============ K1: prep ============
// blocks [0,512): FUSED row stats + raw-exp P write (one logits pass).
// blocks [512,768): normalize x -> xh fp16.
__global__ __launch_bounds__(256) void prep(
    const float* __restrict__ in0, const float* __restrict__ logits0,
    const float* __restrict__ logits1, _Float16* __restrict__ P,
    _Float16* __restrict__ xh, float* __restrict__ alpha,
    float* __restrict__ mll, float* __restrict__ loss) {
  __shared__ float redA[4], redB[4];
  int tid = threadIdx.x, blk = blockIdx.x;
  int wave = tid >> 6, lane = tid & 63;

  if (blk < 512) {
    if (blk == 0 && tid < 3) loss[tid] = 0.0f;  // zero loss accumulators
    int r = blk;
    const float* src = (r < NB) ? logits0 : logits1;
    const float4* row = (const float4*)(src + (size_t)(r & (NB - 1)) * NS);
    float4 v[8];
    float mx = -1e30f;
#pragma unroll
    for (int i = 0; i < 8; ++i) {
      v[i] = row[tid + i * 256];
      mx = fmaxf(mx, fmaxf(fmaxf(v[i].x, v[i].y), fmaxf(v[i].z, v[i].w)));
    }
    float wv = waveMax(mx);
    if (lane == 0) redA[wave] = wv;
    __syncthreads();
    float m = fmaxf(fmaxf(redA[0], redA[1]), fmaxf(redA[2], redA[3]));
    float em = expf(m);
    float se = 0.0f;
    half4* prow = (half4*)(P + (size_t)r * NS);
#pragma unroll
    for (int i = 0; i < 8; ++i) {
      float e0 = expf(v[i].x - m), e1 = expf(v[i].y - m);
      float e2 = expf(v[i].z - m), e3 = expf(v[i].w - m);
      se += (e0 + e1) + (e2 + e3);
      half4 h;
      h[0] = (_Float16)(e0 * em); h[1] = (_Float16)(e1 * em);
      h[2] = (_Float16)(e2 * em); h[3] = (_Float16)(e3 * em);
      prow[tid + i * 256] = h;
    }
    float sw = waveSum(se);
    if (lane == 0) redB[wave] = sw;
    __syncthreads();
    float l = (redB[0] + redB[1]) + (redB[2] + redB[3]);
    if (tid == 0) {
      mll[r] = m + logf(l);
      alpha[r] = 256.0f * expf(-m) / l;
    }
  } else {
    // ---- normalize x -> xh ----
    int b = blk - 512;
    const float4* row = (const float4*)(in0 + (size_t)b * NF);
    float4 v0 = row[tid], v1 = row[tid + 256];
    float ss = v0.x * v0.x + v0.y * v0.y + v0.z * v0.z + v0.w * v0.w +
               v1.x * v1.x + v1.y * v1.y + v1.z * v1.z + v1.w * v1.w;
    float w = waveSum(ss);
    if (lane == 0) redA[wave] = w;
    __syncthreads();
    float tot = (redA[0] + redA[1]) + (redA[2] + redA[3]);
    float inv = 1.0f / fmaxf(sqrtf(tot), 1e-12f);
    half4 h0, h1;
    h0[0] = (_Float16)(v0.x * inv); h0[1] = (_Float16)(v0.y * inv);
    h0[2] = (_Float16)(v0.z * inv); h0[3] = (_Float16)(v0.w * inv);
    h1[0] = (_Float16)(v1.x * inv); h1[1] = (_Float16)(v1.y * inv);
    h1[2] = (_Float16)(v1.z * inv); h1[3] = (_Float16)(v1.w * inv);
    ((half4*)(xh + (size_t)b * NF))[tid] = h0;
    ((half4*)(xh + (size_t)b * NF))[tid + 256] = h1;
  }
}

// ============ K2: A-in-registers GEMM + gather/copy, 1024-thread blocks ============
// blocks [0,256): scores = x@F^T. 16 waves = (mg in [0,8)) x (kg in {0,1}).
//   Wave holds A = 16 rows x (K-subtiles kg,kg+2,..) = 32 half8 = 128 VGPR,
//   loaded ONCE from L2-hot xh. Per tile (N=32, 2 tiles/block): K-loop is
//   {s_barrier; ds_write B from 3-deep fv regs; lgkmcnt(0); s_barrier; 2 MFMA}
//   -- no async16, no stores, no vmcnt drains. kg-pair acc reduced via LDS.
// blocks [256,512): gather block b: 32-row outF copy + full-row sparse
//   20-neighbor CE/KL, atomicAdd out[1],out[2]. 1 GEMM + 1 gather per CU.
__global__ __launch_bounds__(1024) void fused2(
    const _Float16* __restrict__ xh, const float* __restrict__ fB,
    const _Float16* __restrict__ P, const float* __restrict__ alpha,
    const float* __restrict__ mll, const float* __restrict__ logits0,
    const float* __restrict__ logits1, const int* __restrict__ targets,
    const int* __restrict__ neighbors, const float* __restrict__ ndist,
    const float* __restrict__ rampup, float* __restrict__ outF,
    float* __restrict__ pm, float* __restrict__ pl, float* __restrict__ tgt,
    float* __restrict__ out) {
  __shared__ alignas(16) _Float16 Bs[32 * 64];  // 4 KB
  __shared__ alignas(16) float redf[128][32];   // 16 KB (kg-pair acc reduce)
  __shared__ float red[32];
  int tid = threadIdx.x, wave = tid >> 6, lane = tid & 63;
  int quad = lane >> 4, r16 = lane & 15;
  int blk = blockIdx.x;

  if (blk < 256) {
    // XCD-pair swizzle: (blk, blk^8) share the same bx stripe pair
    int by = (blk >> 3) & 1;
    int bxp = (blk & 7) | ((blk >> 4) << 3);  // [0,128)
    int m0 = by * 128;
    int mg = wave >> 1, kg = wave & 1;
    int arow = m0 + mg * 16 + r16;
    int brow = tid >> 3, bq = tid & 7;  // staging threads: tid<256
    // tile-0 fv prologue (issued FIRST: oldest in vmcnt stream, no A-drain)
    float4 fvb[3][2];
    const float* bsrc0 = fB + (size_t)(bxp * 32 + brow) * NF + bq * 8;
    if (tid < 256) {
#pragma unroll
      for (int d = 0; d < 3; ++d) {
        fvb[d][0] = *(const float4*)(bsrc0 + d * 64);
        fvb[d][1] = *(const float4*)(bsrc0 + d * 64 + 4);
      }
    }
    __builtin_amdgcn_sched_barrier(0);
    // A registers: 32 x half8 (16 rows x k = ki*64 + kg*32 + quad*8), L2-hot
    half8 A[32];
    const _Float16* asrc = xh + (size_t)arow * NF + kg * 32 + quad * 8;
#pragma unroll
    for (int ki = 0; ki < 32; ++ki) A[ki] = *(const half8*)(asrc + ki * 64);

    for (int t = 0; t < 2; ++t) {
      int bx = bxp + t * 128;
      int n0 = bx * 32;
      const float* bsrc = fB + (size_t)(n0 + brow) * NF + bq * 8;
      if (t > 0 && tid < 256) {
#pragma unroll
        for (int d = 0; d < 3; ++d) {
          fvb[d][0] = *(const float4*)(bsrc + d * 64);
          fvb[d][1] = *(const float4*)(bsrc + d * 64 + 4);
        }
      }
      f32x4 acc0 = {}, acc1 = {};
#pragma unroll
      for (int ki = 0; ki < 32; ++ki) {
        __builtin_amdgcn_s_barrier();       // Bs(ki-1) consumed by all waves
        __builtin_amdgcn_sched_barrier(0);
        if (tid < 256) {
          float4 va = fvb[ki % 3][0], vb = fvb[ki % 3][1];
          half8 hh;
          hh[0] = (_Float16)va.x; hh[1] = (_Float16)va.y;
          hh[2] = (_Float16)va.z; hh[3] = (_Float16)va.w;
          hh[4] = (_Float16)vb.x; hh[5] = (_Float16)vb.y;
          hh[6] = (_Float16)vb.z; hh[7] = (_Float16)vb.w;
          *(half8*)&Bs[brow * 64 + ((bq ^ (brow & 7)) << 3)] = hh;
          if (ki < 29) {  // re-issue this slot 3 iters ahead (~900cy cover)
            fvb[ki % 3][0] = *(const float4*)(bsrc + (ki + 3) * 64);
            fvb[ki % 3][1] = *(const float4*)(bsrc + (ki + 3) * 64 + 4);
          }
        }
        __builtin_amdgcn_sched_barrier(0);
        asm volatile("s_waitcnt lgkmcnt(0)");  // ds_write landed (no vmcnt!)
        __builtin_amdgcn_sched_barrier(0);
        __builtin_amdgcn_s_barrier();          // Bs(ki) visible to all
        __builtin_amdgcn_sched_barrier(0);
        int slot = ((kg * 4 + quad) ^ (r16 & 7)) * 8;
        half8 bf0 = *(const half8*)&Bs[r16 * 64 + slot];
        half8 bf1 = *(const half8*)&Bs[(16 + r16) * 64 + slot];
        acc0 = __builtin_amdgcn_mfma_f32_16x16x32_f16(A[ki], bf0, acc0, 0, 0, 0);
        acc1 = __builtin_amdgcn_mfma_f32_16x16x32_f16(A[ki], bf1, acc1, 0, 0, 0);
      }
      // kg-pair accumulator reduce via LDS, then LSE epilogue on kg=0 waves
      if (kg == 1) {
#pragma unroll
        for (int r = 0; r < 4; ++r) {
          redf[mg * 16 + quad * 4 + r][r16] = acc0[r];
          redf[mg * 16 + quad * 4 + r][16 + r16] = acc1[r];
        }
      }
      __syncthreads();
      if (kg == 0) {
#pragma unroll
        for (int r = 0; r < 4; ++r) {
          int rr = mg * 16 + quad * 4 + r;
          float s0 = (acc0[r] + redf[rr][r16]) * 20.0f;        // 1/TEMP
          float s1 = (acc1[r] + redf[rr][16 + r16]) * 20.0f;
          float mx = fmaxf(s0, s1);
#pragma unroll
          for (int m2 = 1; m2 < 16; m2 <<= 1) mx = fmaxf(mx, __shfl_xor(mx, m2, 64));
          float e = expf(s0 - mx) + expf(s1 - mx);
#pragma unroll
          for (int m2 = 1; m2 < 16; m2 <<= 1) e += __shfl_xor(e, m2, 64);
          int R = m0 + rr;
          int tg = targets[R];
          if (n0 + r16 == tg) tgt[R] = s0;
          if (n0 + 16 + r16 == tg) tgt[R] = s1;
          if (r16 == 0) { pm[R * 256 + bx] = mx; pl[R * 256 + bx] = e; }
        }
      }
      __syncthreads();
    }
  } else {
    // ---- gather block b: outF copy (32 rows) + full-row sparse CE/KL ----
    int b = blk - 256;
    {
      const float4* srcc = (const float4*)fB + (size_t)b * 32 * 512;
      float4* dstc = (float4*)outF + (size_t)b * 32 * 512;
#pragma unroll
      for (int i = 0; i < 16; ++i) dstc[tid + i * 1024] = srcc[tid + i * 1024];
    }
    float s = 0.0f;
    int cnt = 0;
#pragma unroll
    for (int k = 0; k < NK; ++k) {
      float d = ndist[b * NK + k];
      s += expf(d * (1.0f / 0.6f));
      cnt += (d <= 2.0f) ? 1 : 0;
    }
    float invs = 1.0f / (2.0f * s);
    float invc = 1.0f / fmaxf((float)cnt, 1.0f);
    float ce[8] = {0, 0, 0, 0, 0, 0, 0, 0};
    float kl[8] = {0, 0, 0, 0, 0, 0, 0, 0};
    int sc_ = tid * 8;
#pragma unroll 4
    for (int k = 0; k < NK; ++k) {
      float d = ndist[b * NK + k];
      int n = neighbors[b * NK + k];
      float wce = expf(d * (1.0f / 0.6f)) * invs;
      float wkl = (d <= 2.0f) ? invc : 0.0f;
      float a0 = alpha[n], a1 = alpha[256 + n];
      float c0 = wce * a0, c1 = wce * a1, ck = wkl * a0;
      half8 p0 = *(const half8*)(P + (size_t)n * NS + sc_);
      half8 p1 = *(const half8*)(P + (size_t)(256 + n) * NS + sc_);
#pragma unroll
      for (int e2 = 0; e2 < 8; ++e2) {
        float q0 = (float)p0[e2], q1 = (float)p1[e2];
        ce[e2] += c0 * q0 + c1 * q1;
        kl[e2] += ck * q0;
      }
    }
    float mv0 = mll[b], mv1 = mll[256 + b];
    const float* g0 = logits0 + (size_t)b * NS + sc_;
    const float* g1 = logits1 + (size_t)b * NS + sc_;
    float4 l0a = *(const float4*)g0, l0b = *(const float4*)(g0 + 4);
    float4 l1a = *(const float4*)g1, l1b = *(const float4*)(g1 + 4);
    float lg0[8] = {l0a.x, l0a.y, l0a.z, l0a.w, l0b.x, l0b.y, l0b.z, l0b.w};
    float lg1[8] = {l1a.x, l1a.y, l1a.z, l1a.w, l1b.x, l1b.y, l1b.z, l1b.w};
    float lce = 0.0f, lkl = 0.0f;
#pragma unroll
    for (int e2 = 0; e2 < 8; ++e2) {
      float t = ce[e2] * (1.0f / 256.0f);
      lce += t * (lg0[e2] - mv0);
      float tk = kl[e2] * (1.0f / 256.0f);
      lkl += (tk > 0.0f) ? tk * (logf(fmaxf(tk, 1e-12f)) - (lg1[e2] - mv1)) : 0.0f;
    }
    float wc = waveSum(lce), wk = waveSum(lkl);
    if (lane == 0) { red[wave] = wc; red[16 + wave] = wk; }
    __syncthreads();
    if (tid == 0) {
      float ce_t = 0.0f, kl_t = 0.0f;
#pragma unroll
      for (int i = 0; i < 16; ++i) { ce_t += red[i]; kl_t += red[16 + i]; }
      atomicAdd(out + 1, -0.1f * ce_t * (1.0f / 256.0f));
      atomicAdd(out + 2, rampup[0] * kl_t * (1.0f / 256.0f));
    }
  }
}

// ============ K3: finalize + momentum winner rows ============
// blocks [0,256): LSE over 256 stripes of row b + CE-onehot -> atomics
// blocks [256,512): momentum winner rows overwrite outF[targets[b]].
__global__ __launch_bounds__(128) void final_reduce(
    const float* __restrict__ pm, const float* __restrict__ pl,
    const float* __restrict__ tgt, const float* __restrict__ logits0,
    const float* __restrict__ mll, const int* __restrict__ targets,
    const float* __restrict__ in0, const float* __restrict__ features,
    float* __restrict__ outF, float* __restrict__ out) {
  __shared__ float rA[2], rB[2];
  __shared__ int flag;
  int tid = threadIdx.x, blk = blockIdx.x;
  if (blk < 256) {
    int b = blk;
    float m1 = pm[b * 256 + tid], m2v = pm[b * 256 + 128 + tid];
    float l1 = pl[b * 256 + tid], l2v = pl[b * 256 + 128 + tid];
    float wm = waveMax(fmaxf(m1, m2v));
    if ((tid & 63) == 0) rA[tid >> 6] = wm;
    __syncthreads();
    float mx = fmaxf(rA[0], rA[1]);
    float e = l1 * expf(m1 - mx) + l2v * expf(m2v - mx);
    float ws = waveSum(e);
    if ((tid & 63) == 0) rB[tid >> 6] = ws;
    __syncthreads();
    if (tid == 0) {
      float S = rB[0] + rB[1];
      float nce = -(tgt[b] - mx - logf(S));
      int tg = targets[b];
      float oh = -0.9f * (logits0[(size_t)b * NS + tg] - mll[b]);
      atomicAdd(out + 0, nce * (1.0f / 256.0f));
      atomicAdd(out + 1, oh * (1.0f / 256.0f));
    }
  } else {
    int b = blk - 256;
    int tg = targets[b];
    if (tid == 0) flag = 0;
    __syncthreads();
    bool later = false;
    for (int i = b + 1 + tid; i < 256; i += 128) later = later || (targets[i] == tg);
    if (later) flag = 1;
    __syncthreads();
    if (flag) return;  // some later batch row owns this target
    const float4* xr = (const float4*)(in0 + (size_t)b * NF);
    const float4* fr = (const float4*)(features + (size_t)tg * NF);
    float4 a[4];
    float ssx = 0.0f;
#pragma unroll
    for (int s = 0; s < 4; ++s) {
      a[s] = xr[tid + s * 128];
      ssx += a[s].x * a[s].x + a[s].y * a[s].y + a[s].z * a[s].z + a[s].w * a[s].w;
    }
    float w1 = waveSum(ssx);
    if ((tid & 63) == 0) rA[tid >> 6] = w1;
    __syncthreads();
    float ix = 0.8f / fmaxf(sqrtf(rA[0] + rA[1]), 1e-12f);
    float4 v[4];
    float ss = 0.0f;
#pragma unroll
    for (int s = 0; s < 4; ++s) {
      float4 f = fr[tid + s * 128];
      v[s] = make_float4(0.2f * f.x + ix * a[s].x, 0.2f * f.y + ix * a[s].y,
                         0.2f * f.z + ix * a[s].z, 0.2f * f.w + ix * a[s].w);
      ss += v[s].x * v[s].x + v[s].y * v[s].y + v[s].z * v[s].z + v[s].w * v[s].w;
    }
    float w2 = waveSum(ss);
    if ((tid & 63) == 0) rB[tid >> 6] = w2;
    __syncthreads();
    float inv = 1.0f / fmaxf(sqrtf(rB[0] + rB[1]), 1e-12f);
    float4* o4 = (float4*)(outF + (size_t)tg * NF);
#pragma unroll
    for (int s = 0; s < 4; ++s)
      o4[tid + s * 128] = make_float4(v[s].x * inv, v[s].y * inv, v[s].z * inv, v[s].w * inv);
  }
}

extern "C" void kernel_launch(void* const* d_in, const int* in_sizes, int n_in,
                              void* d_out, int out_size, void* d_ws, size_t ws_size,
                              hipStream_t stream) {
  const float* inputs0 = (const float*)d_in[0];
  const float* logits0 = (const float*)d_in[1];
  const float* logits1 = (const float*)d_in[2];
  const int* targets = (const int*)d_in[3];
  const int* neighbors = (const int*)d_in[5];
  const float* ndist = (const float*)d_in[6];
  const float* rampup = (const float*)d_in[7];
  const float* features = (const float*)d_in[8];
  float* out = (float*)d_out;

  char* ws = (char*)d_ws;
  float* mll = (float*)(ws + 4096);            // 2 KB
  float* alpha = (float*)(ws + 8192);          // 2 KB (f32)
  float* tgt = (float*)(ws + 16384);           // 1 KB
  float* pm = (float*)(ws + 65536);            // 256 KB (256 rows x 256 stripes)
  float* pl = (float*)(ws + 65536 + 262144);   // 256 KB
  _Float16* xh = (_Float16*)(ws + (3 << 20));  // 1 MB
  _Float16* P = (_Float16*)(ws + (4 << 20));   // 8 MB (row-major raw exp)

  prep<<<768, 256, 0, stream>>>(inputs0, logits0, logits1, P, xh, alpha, mll, out);
  fused2<<<512, 1024, 0, stream>>>(xh, features, P, alpha, mll, logits0, logits1,
                                   targets, neighbors, ndist, rampup, out + 3,
                                   pm, pl, tgt, out);
  final_reduce<<<512, 128, 0, stream>>>(pm, pl, tgt, logits0, mll, targets,
                                        inputs0, features, out + 3, out);
}